// Round 3
// baseline (384.965 us; speedup 1.0000x reference)
//
#include <hip/hip_runtime.h>
#include <hip/hip_bf16.h>
#include <math.h>

// ---------------- constants ----------------
#define BSZ     2
#define TLEN    4096
#define DMODEL  1024
#define DINNER  2048
#define DSTATE  64
#define NHEADS  32
#define HEADDIM 64
#define CHUNK   64
#define NCHUNK  64            // TLEN / CHUNK
#define CONVDIM 2176          // DINNER + 2*DSTATE
#define DPROJ   4256          // 2*DINNER + 2*DSTATE + NHEADS
#define ROWS    8192          // BSZ*TLEN
#define LDP     72            // 64 + 8 pad (shorts) for MFMA LDS tiles
#define LDE     136           // 128 + 8 pad (shorts) for gemm epilogue tile
#define BUFSH   24576         // (256+128)*64 shorts per pipeline buffer

typedef __attribute__((ext_vector_type(8))) short s16x8;
typedef __attribute__((ext_vector_type(4))) short s16x4;
typedef __attribute__((ext_vector_type(4))) float f32x4;

__device__ __forceinline__ float bf2f(__hip_bfloat16 x) { return __bfloat162float(x); }
__device__ __forceinline__ __hip_bfloat16 f2bf(float x) { return __float2bfloat16(x); }
__device__ __forceinline__ short f2bf_s(float x) {
  union { __hip_bfloat16 h; short s; } c; c.h = __float2bfloat16(x); return c.s;
}
__device__ __forceinline__ float s2f(short s) {
  union { unsigned int u; float f; } c; c.u = ((unsigned int)(unsigned short)s) << 16; return c.f;
}
__device__ __forceinline__ s16x8 scale8(s16x8 a, float s) {
  s16x8 r;
#pragma unroll
  for (int i = 0; i < 8; ++i) r[i] = f2bf_s(s2f(a[i]) * s);
  return r;
}

#define GLDS16(g, l)                                                        \
  __builtin_amdgcn_global_load_lds(                                         \
      (const __attribute__((address_space(1))) void*)(g),                   \
      (__attribute__((address_space(3))) void*)(l), 16, 0, 0)

// fused counted-wait + barrier (single asm: nothing schedules between them)
#define WAIT_BAR(N) asm volatile("s_waitcnt vmcnt(" #N ")\n\ts_barrier" ::: "memory")
// plain barrier with memory clobber (pins ds_read/STAGE issue on its side)
#define BARRIER     asm volatile("s_barrier" ::: "memory")

// ---------------- f32 -> bf16 casts ----------------
__global__ __launch_bounds__(256) void cast_f32_bf16(
    const float* __restrict__ src, __hip_bfloat16* __restrict__ dst, int n) {
  const int i = (blockIdx.x * 256 + threadIdx.x) * 4;
  if (i + 3 < n) {
    const f32x4 v = *(const f32x4*)(src + i);
    dst[i + 0] = f2bf(v[0]); dst[i + 1] = f2bf(v[1]);
    dst[i + 2] = f2bf(v[2]); dst[i + 3] = f2bf(v[3]);
  } else {
    for (int j = i; j < n; ++j) dst[j] = f2bf(src[j]);
  }
}

__global__ __launch_bounds__(256) void cast2_f32_bf16(
    const float* __restrict__ s1, __hip_bfloat16* __restrict__ d1, int n1,
    const float* __restrict__ s2, __hip_bfloat16* __restrict__ d2, int n2) {
  const int i = (blockIdx.x * 256 + threadIdx.x) * 4;   // n1, n2 divisible by 4
  if (i < n1) {
    const f32x4 v = *(const f32x4*)(s1 + i);
    d1[i + 0] = f2bf(v[0]); d1[i + 1] = f2bf(v[1]);
    d1[i + 2] = f2bf(v[2]); d1[i + 3] = f2bf(v[3]);
  } else {
    const int j = i - n1;
    if (j < n2) {
      const f32x4 v = *(const f32x4*)(s2 + j);
      d2[j + 0] = f2bf(v[0]); d2[j + 1] = f2bf(v[1]);
      d2[j + 2] = f2bf(v[2]); d2[j + 3] = f2bf(v[3]);
    }
  }
}

// ---------------- pipelined GEMM: C = A[M][K] @ B[N][K]^T ----------------
// 256x128 tile, 8 waves (4M x 2N), BK=64, 3-deep LDS pipeline, counted
// vmcnt. r3 change: PHASE-SPLIT K-step (T3) — each K-tile is 2 phases of
// { 8 ds_read_b128 (one sub) || issue half of K-tile t+2's stage (3 loads)
//   -> s_barrier -> setprio(1) + 16 MFMA + setprio(0) -> barrier }.
// The double-barrier-per-phase creates the wave role-split (T5 pays);
// counted vmcnt(6) only at the END-of-K-tile barrier (never mid-tile,
// never 0 in steady state). Hazards: reads of buf complete (register dep)
// before the wave's tile-end barrier; STAGE into that buf issues only
// after it -> no WAR. RAW = same vmcnt(6) accounting r2 proved correct.
// SPLIT=1 (in-proj): operand-SWAPPED mfma -> acc holds 4 consecutive COLS.
// SPLIT=0 (out-proj): unswapped, scalar coalesced f32 stores.
template <int SPLIT>
__global__ __launch_bounds__(512) void gemm_tiled(
    const short* __restrict__ A, const short* __restrict__ B,
    __hip_bfloat16* __restrict__ Cz, __hip_bfloat16* __restrict__ Cx,
    float* __restrict__ Cd, float* __restrict__ Cout, int M, int N, int K) {
  __shared__ __align__(16) short smem[3 * BUFSH];   // 147456 B; epilogue aliases
  const int tid  = threadIdx.x;
  const int wave = tid >> 6, lane = tid & 63;
  const int lhi  = lane >> 4, llo = lane & 15;
  const int wm   = wave >> 1, wn = wave & 1;       // 4M x 2N wave grid
  const int tm   = blockIdx.x * 256, tn = blockIdx.y * 128;
  const int srow = lane >> 3;                      // 0..7 (row within 1KB chunk)
  const int skc  = ((lane & 7) ^ srow) * 8;        // pre-swizzled global k-chunk
  const int nk   = K >> 6;                         // K-tiles (>= 3 here)

  f32x4 acc[4][4];
  const f32x4 fz = {0.f, 0.f, 0.f, 0.f};
#pragma unroll
  for (int mi = 0; mi < 4; ++mi)
#pragma unroll
    for (int ni = 0; ni < 4; ++ni) acc[mi][ni] = fz;

  // half-stage: A-chunks {2h, 2h+1} + B-chunk {h} -> 3 vmcnt events
  auto STAGE_HALF = [&](int bi, int k0, int h) {
    short* bA = smem + bi * BUFSH;
    short* bB = bA + 256 * 64;
#pragma unroll
    for (int i = 0; i < 2; ++i) {
      const int ca = (2 * h + i) * 8 + wave;       // 0..31  (A: 256 rows)
      const int rl = ca * 8 + srow;
      GLDS16(A + (size_t)(tm + rl) * K + k0 + skc, bA + ca * 512);
    }
    {
      const int cb = h * 8 + wave;                 // 0..15  (B: 128 rows)
      const int rl = cb * 8 + srow;
      GLDS16(B + (size_t)(tn + rl) * K + k0 + skc, bB + cb * 512);
    }
  };

  // prologue: stage K-tiles 0 and 1 fully; wait tile 0 (tile 1 in flight)
  STAGE_HALF(0, 0, 0);  STAGE_HALF(0, 0, 1);
  STAGE_HALF(1, 64, 0); STAGE_HALF(1, 64, 1);
  WAIT_BAR(6);

  for (int t = 0; t < nk; ++t) {
    const short* bA = smem + (t % 3) * BUFSH;
    const short* bB = bA + 256 * 64;
    const bool pf = (t + 2 < nk);
    const int pbi = (t + 2) % 3;
    const int pk0 = (t + 2) << 6;
#pragma unroll
    for (int sub = 0; sub < 2; ++sub) {
      s16x8 af[4], bfr[4];
#pragma unroll
      for (int i = 0; i < 4; ++i) {
        const int am = wm * 64 + i * 16 + llo;
        af[i]  = *(const s16x8*)(bA + am * 64 + (((sub << 2) + lhi) ^ (am & 7)) * 8);
        const int bn = wn * 64 + i * 16 + llo;
        bfr[i] = *(const s16x8*)(bB + bn * 64 + (((sub << 2) + lhi) ^ (bn & 7)) * 8);
      }
      if (pf) STAGE_HALF(pbi, pk0, sub);
      BARRIER;                                   // all waves issued reads+stage
      __builtin_amdgcn_s_setprio(1);
#pragma unroll
      for (int mi = 0; mi < 4; ++mi)
#pragma unroll
        for (int ni = 0; ni < 4; ++ni)
          acc[mi][ni] = SPLIT
            ? __builtin_amdgcn_mfma_f32_16x16x32_bf16(bfr[ni], af[mi], acc[mi][ni], 0, 0, 0)
            : __builtin_amdgcn_mfma_f32_16x16x32_bf16(af[mi], bfr[ni], acc[mi][ni], 0, 0, 0);
      __builtin_amdgcn_s_setprio(0);
      if (sub == 0) BARRIER;                     // phase pacing barrier
    }
    // end of K-tile: counted wait fused with barrier (t+1 resident, t+2 flies)
    if (pf) WAIT_BAR(6);
    else    WAIT_BAR(0);
  }

  if (SPLIT) {
    // swapped layout: out_row = ...+llo, out_col = ...+lhi*4+r (4 consecutive cols)
    if (blockIdx.y < 33) {
      // vectorized path via LDS transpose (region uniform per block)
#pragma unroll
      for (int mi = 0; mi < 4; ++mi)
#pragma unroll
        for (int ni = 0; ni < 4; ++ni) {
          const int rl = wm * 64 + mi * 16 + llo;
          const int cl = wn * 64 + ni * 16 + lhi * 4;
          s16x4 v;
#pragma unroll
          for (int r = 0; r < 4; ++r) v[r] = f2bf_s(acc[mi][ni][r]);
          *(s16x4*)(smem + rl * LDE + cl) = v;
        }
      __syncthreads();
      const int rl = tid >> 1;                 // 0..255
      const int ch = (tid & 1) * 64;
      const short* src = smem + rl * LDE + ch;
      short* gp;
      if (blockIdx.y < 16)
        gp = (short*)Cz + (size_t)(tm + rl) * DINNER + tn + ch;
      else
        gp = (short*)Cx + (size_t)(tm + rl) * CONVDIM + (tn - DINNER) + ch;
#pragma unroll
      for (int j = 0; j < 8; ++j)
        *(s16x8*)(gp + j * 8) = *(const s16x8*)(src + j * 8);
    } else {
      // dt tile: cols 4224..4256 valid (local 0..32) -> f32, scalar
#pragma unroll
      for (int mi = 0; mi < 4; ++mi)
#pragma unroll
        for (int ni = 0; ni < 4; ++ni)
#pragma unroll
          for (int r = 0; r < 4; ++r) {
            const int col = wn * 64 + ni * 16 + lhi * 4 + r;
            if (col < NHEADS) {
              const int row = tm + wm * 64 + mi * 16 + llo;
              Cd[(size_t)row * NHEADS + col] = acc[mi][ni][r];
            }
          }
    }
  } else {
#pragma unroll
    for (int mi = 0; mi < 4; ++mi)
#pragma unroll
      for (int ni = 0; ni < 4; ++ni)
#pragma unroll
        for (int r = 0; r < 4; ++r) {
          const int row = tm + wm * 64 + mi * 16 + lhi * 4 + r;
          const int col = tn + wn * 64 + ni * 16 + llo;
          Cout[(size_t)row * N + col] = acc[mi][ni][r];
        }
  }
}

// ---------------- conv1d (depthwise, causal, width 4) + SiLU — vectorized 8 ch/thread ----------------
__global__ __launch_bounds__(256) void conv_silu_kernel(
    const __hip_bfloat16* __restrict__ xBC, const float* __restrict__ conv_w,
    const float* __restrict__ conv_b, __hip_bfloat16* __restrict__ convOut) {
  const int idx8 = blockIdx.x * 256 + threadIdx.x;   // bt*272 + c8
  const int c8 = idx8 % 272;
  const int bt = idx8 / 272;
  if (bt >= ROWS) return;
  const int t = bt & (TLEN - 1);
  const int c = c8 * 8;
  const short* xp = (const short*)xBC;

  f32x4 w4[8];
#pragma unroll
  for (int j = 0; j < 8; ++j) w4[j] = *(const f32x4*)(conv_w + (c + j) * 4);

  float acc[8];
  const f32x4 b0 = *(const f32x4*)(conv_b + c);
  const f32x4 b1 = *(const f32x4*)(conv_b + c + 4);
#pragma unroll
  for (int j = 0; j < 4; ++j) { acc[j] = b0[j]; acc[4 + j] = b1[j]; }

#pragma unroll
  for (int k = 0; k < 4; ++k) {
    const int tt = t - 3 + k;
    if (tt < 0) continue;
    const s16x8 xv = *(const s16x8*)(xp + (size_t)(bt - 3 + k) * CONVDIM + c);
#pragma unroll
    for (int j = 0; j < 8; ++j) acc[j] += w4[j][k] * s2f(xv[j]);
  }
  s16x8 o;
#pragma unroll
  for (int j = 0; j < 8; ++j) {
    const float s = acc[j] / (1.f + expf(-acc[j]));
    o[j] = f2bf_s(s);
  }
  *(s16x8*)((short*)convOut + (size_t)bt * CONVDIM + c) = o;
}

// ---------------- dt softplus + per-chunk cumsum of A*dt — one wave per (b,h,chunk) ----------------
__global__ __launch_bounds__(256) void dt_cumsum_kernel(
    const float* __restrict__ dt_raw, const float* __restrict__ dt_bias,
    const float* __restrict__ A_log, float* __restrict__ dt_sp, float* __restrict__ cum) {
  const int lane = threadIdx.x & 63;
  const int w = blockIdx.x * 4 + (threadIdx.x >> 6);   // bh*64 + c
  const int c = w & 63, bh = w >> 6;
  const int h = bh & 31, b = bh >> 5;
  const int t = c * CHUNK + lane;
  const float raw = dt_raw[((size_t)(b * TLEN + t)) * NHEADS + h] + dt_bias[h];
  const float d = (raw > 20.f) ? raw : log1pf(expf(raw));
  float v = -expf(A_log[h]) * d;
#pragma unroll
  for (int off = 1; off < 64; off <<= 1) {
    const float nb = __shfl_up(v, off, 64);
    if (lane >= off) v += nb;
  }
  dt_sp[(size_t)bh * TLEN + t] = d;
  cum[(size_t)bh * TLEN + t] = v;
}

// ---------------- per-chunk state (MFMA): cs[p][n] = sum_l xd[l][p]*B[l][n] ----------------
__global__ __launch_bounds__(256) void chunk_state_kernel(
    const __hip_bfloat16* __restrict__ convOut, const float* __restrict__ dt_sp,
    const float* __restrict__ cum, __hip_bfloat16* __restrict__ chunk_states) {
  __shared__ __align__(16) short sBT [64 * LDP];   // B^T [n][l]
  __shared__ __align__(16) short sXdT[64 * LDP];   // xd^T [p][l]
  const int c = blockIdx.x, h = blockIdx.y, b = blockIdx.z;
  const int tid = threadIdx.x;
  const int wave = tid >> 6, lane = tid & 63;
  const int lhi = lane >> 4, llo = lane & 15;
  const int bh = b * NHEADS + h;
  const float cumL = cum[(size_t)bh * TLEN + c * CHUNK + 63];
  const short* cOut = (const short*)convOut;

  for (int v = tid; v < 512; v += 256) {
    const int l = v >> 3, ch = v & 7;
    const size_t rowoff = ((size_t)(b * TLEN + c * CHUNK + l)) * CONVDIM;
    const s16x8 bv = *(const s16x8*)(cOut + rowoff + DINNER + ch * 8);
    const float wgt = dt_sp[(size_t)bh * TLEN + c * CHUNK + l] *
                      expf(cumL - cum[(size_t)bh * TLEN + c * CHUNK + l]);
    const s16x8 xv = *(const s16x8*)(cOut + rowoff + h * HEADDIM + ch * 8);
#pragma unroll
    for (int jj = 0; jj < 8; ++jj) {
      sBT [(ch * 8 + jj) * LDP + l] = bv[jj];
      sXdT[(ch * 8 + jj) * LDP + l] = f2bf_s(s2f(xv[jj]) * wgt);
    }
  }
  __syncthreads();

  const f32x4 fz = {0.f, 0.f, 0.f, 0.f};
  const s16x8 a0 = *(const s16x8*)(sXdT + (16 * wave + llo) * LDP + lhi * 8);
  const s16x8 a1 = *(const s16x8*)(sXdT + (16 * wave + llo) * LDP + 32 + lhi * 8);
  const size_t outb = ((((size_t)b * NCHUNK + c) * NHEADS + h) * HEADDIM) * DSTATE;
#pragma unroll
  for (int j = 0; j < 4; ++j) {
    const s16x8 b0 = *(const s16x8*)(sBT + (16 * j + llo) * LDP + lhi * 8);
    const s16x8 b1 = *(const s16x8*)(sBT + (16 * j + llo) * LDP + 32 + lhi * 8);
    f32x4 acc = fz;
    acc = __builtin_amdgcn_mfma_f32_16x16x32_bf16(a0, b0, acc, 0, 0, 0);
    acc = __builtin_amdgcn_mfma_f32_16x16x32_bf16(a1, b1, acc, 0, 0, 0);
#pragma unroll
    for (int r = 0; r < 4; ++r) {
      const int p = 16 * wave + lhi * 4 + r;
      const int n = 16 * j + llo;
      chunk_states[outb + (size_t)p * DSTATE + n] = f2bf(acc[r]);
    }
  }
}

// ---------------- inter-chunk scan, IN-PLACE ----------------
__global__ __launch_bounds__(256) void scan_kernel(
    __hip_bfloat16* __restrict__ cs, const float* __restrict__ cum) {
  const int idx = blockIdx.x * 256 + threadIdx.x;
  const int n = idx & 63;
  int r = idx >> 6;
  const int p = r & 63; r >>= 6;
  const int h = r & 31;
  const int b = r >> 5;
  const int bh = b * NHEADS + h;
  const size_t stride_c = (size_t)NHEADS * HEADDIM * DSTATE;
  const size_t base = ((size_t)b * NCHUNK) * stride_c + ((size_t)h * HEADDIM + p) * DSTATE + n;
  float s = 0.f;
  for (int c = 0; c < NCHUNK; ++c) {
    const size_t off = base + (size_t)c * stride_c;
    const float val = bf2f(cs[off]);
    cs[off] = f2bf(s);
    const float dec = expf(cum[(size_t)bh * TLEN + c * CHUNK + 63]);
    s = dec * s + val;
  }
}

// ---------------- per-chunk output (MFMA) ----------------
__global__ __launch_bounds__(256) void y_kernel(
    const __hip_bfloat16* __restrict__ convOut, const float* __restrict__ dt_sp,
    const float* __restrict__ cum, const __hip_bfloat16* __restrict__ states_pre,
    const float* __restrict__ Dparam, __hip_bfloat16* __restrict__ Yraw) {
  __shared__ __align__(16) short sC [64 * LDP];   // C[l][n]
  __shared__ __align__(16) short sBW[64 * LDP];   // phase1: B[s][n]; phase3: W[l][s]
  __shared__ __align__(16) short sXT[64 * LDP];   // xdt^T [p][s]
  __shared__ __align__(16) short sSP[64 * LDP];   // SP[p][n]
  __shared__ float scum[64];
  const int c = blockIdx.x, h = blockIdx.y, b = blockIdx.z;
  const int tid = threadIdx.x;
  const int wave = tid >> 6, lane = tid & 63;
  const int lhi = lane >> 4, llo = lane & 15;
  const int bh = b * NHEADS + h;
  const size_t tbase = (size_t)(b * TLEN + c * CHUNK);
  const short* cOut = (const short*)convOut;
  const size_t spbase = ((((size_t)b * NCHUNK + c) * NHEADS + h) * HEADDIM) * DSTATE;
  const f32x4 fz = {0.f, 0.f, 0.f, 0.f};

  for (int v = tid; v < 512; v += 256) {
    const int r = v >> 3, ch = v & 7;
    const size_t rowoff = (tbase + r) * CONVDIM;
    *(s16x8*)(sC  + r * LDP + ch * 8) = *(const s16x8*)(cOut + rowoff + DINNER + DSTATE + ch * 8);
    *(s16x8*)(sBW + r * LDP + ch * 8) = *(const s16x8*)(cOut + rowoff + DINNER + ch * 8);
    *(s16x8*)(sSP + r * LDP + ch * 8) = *(const s16x8*)((const short*)states_pre + spbase + r * 64 + ch * 8);
    const float dt = dt_sp[(size_t)bh * TLEN + c * CHUNK + r];
    const s16x8 xv = *(const s16x8*)(cOut + rowoff + h * HEADDIM + ch * 8);
#pragma unroll
    for (int jj = 0; jj < 8; ++jj)
      sXT[(ch * 8 + jj) * LDP + r] = f2bf_s(s2f(xv[jj]) * dt);
  }
  if (tid < 64) scum[tid] = cum[(size_t)bh * TLEN + c * CHUNK + tid];
  __syncthreads();

  // phase 1: G[l][s]
  const s16x8 aC0 = *(const s16x8*)(sC + (16 * wave + llo) * LDP + lhi * 8);
  const s16x8 aC1 = *(const s16x8*)(sC + (16 * wave + llo) * LDP + 32 + lhi * 8);
  f32x4 g[4];
#pragma unroll
  for (int j = 0; j < 4; ++j) {
    const s16x8 b0 = *(const s16x8*)(sBW + (16 * j + llo) * LDP + lhi * 8);
    const s16x8 b1 = *(const s16x8*)(sBW + (16 * j + llo) * LDP + 32 + lhi * 8);
    f32x4 acc = fz;
    acc = __builtin_amdgcn_mfma_f32_16x16x32_bf16(aC0, b0, acc, 0, 0, 0);
    acc = __builtin_amdgcn_mfma_f32_16x16x32_bf16(aC1, b1, acc, 0, 0, 0);
    g[j] = acc;
  }
  __syncthreads();

  // phase 2: W[l][s] = (s<=l) ? G*exp(cum[l]-cum[s]) : 0
  float cl[4];
#pragma unroll
  for (int r = 0; r < 4; ++r) cl[r] = scum[16 * wave + lhi * 4 + r];
#pragma unroll
  for (int j = 0; j < 4; ++j) {
    const int s = 16 * j + llo;
    const float cs_ = scum[s];
#pragma unroll
    for (int r = 0; r < 4; ++r) {
      const int l = 16 * wave + lhi * 4 + r;
      const float v = (s <= l) ? g[j][r] * expf(cl[r] - cs_) : 0.f;
      sBW[l * LDP + s] = f2bf_s(v);
    }
  }
  __syncthreads();

  // phase 3: Y[l][p]
  const float el = expf(scum[16 * wave + llo]);
  const s16x8 aCs0 = scale8(aC0, el);
  const s16x8 aCs1 = scale8(aC1, el);
  const s16x8 aW0 = *(const s16x8*)(sBW + (16 * wave + llo) * LDP + lhi * 8);
  const s16x8 aW1 = *(const s16x8*)(sBW + (16 * wave + llo) * LDP + 32 + lhi * 8);
  const float Dh = Dparam[h];
#pragma unroll
  for (int j = 0; j < 4; ++j) {
    const s16x8 bx0 = *(const s16x8*)(sXT + (16 * j + llo) * LDP + lhi * 8);
    const s16x8 bx1 = *(const s16x8*)(sXT + (16 * j + llo) * LDP + 32 + lhi * 8);
    const s16x8 bs0 = *(const s16x8*)(sSP + (16 * j + llo) * LDP + lhi * 8);
    const s16x8 bs1 = *(const s16x8*)(sSP + (16 * j + llo) * LDP + 32 + lhi * 8);
    f32x4 acc = fz;
    acc = __builtin_amdgcn_mfma_f32_16x16x32_bf16(aW0, bx0, acc, 0, 0, 0);
    acc = __builtin_amdgcn_mfma_f32_16x16x32_bf16(aW1, bx1, acc, 0, 0, 0);
    acc = __builtin_amdgcn_mfma_f32_16x16x32_bf16(aCs0, bs0, acc, 0, 0, 0);
    acc = __builtin_amdgcn_mfma_f32_16x16x32_bf16(aCs1, bs1, acc, 0, 0, 0);
#pragma unroll
    for (int r = 0; r < 4; ++r) {
      const int l = 16 * wave + lhi * 4 + r;
      const int p = 16 * j + llo;
      const size_t row = tbase + l;
      const float xval = bf2f(convOut[row * CONVDIM + h * HEADDIM + p]);
      Yraw[row * DINNER + h * HEADDIM + p] = f2bf(acc[r] + Dh * xval);
    }
  }
}

// ---------------- gate (silu(z)) + RMSNorm -> bf16 ----------------
__global__ __launch_bounds__(256) void gate_norm_kernel(
    const __hip_bfloat16* __restrict__ Yraw, const __hip_bfloat16* __restrict__ z,
    const float* __restrict__ norm_w, __hip_bfloat16* __restrict__ ybf) {
  const int row = blockIdx.x;
  const int tid = threadIdx.x;
  const size_t base = (size_t)row * DINNER + tid * 8;
  const s16x8 yv8 = *(const s16x8*)((const short*)Yraw + base);
  const s16x8 zv8 = *(const s16x8*)((const short*)z + base);
  float vals[8];
  float ss = 0.f;
#pragma unroll
  for (int j = 0; j < 8; ++j) {
    const float zv = s2f(zv8[j]);
    const float v = s2f(yv8[j]) * (zv / (1.f + expf(-zv)));
    vals[j] = v;
    ss += v * v;
  }
#pragma unroll
  for (int off = 32; off > 0; off >>= 1) ss += __shfl_down(ss, off, 64);
  __shared__ float red[4];
  if ((tid & 63) == 0) red[tid >> 6] = ss;
  __syncthreads();
  const float rms = rsqrtf((red[0] + red[1] + red[2] + red[3]) / (float)DINNER + 1e-5f);
  const f32x4 nw0 = *(const f32x4*)(norm_w + tid * 8);
  const f32x4 nw1 = *(const f32x4*)(norm_w + tid * 8 + 4);
  s16x8 o;
#pragma unroll
  for (int j = 0; j < 4; ++j) {
    o[j]     = f2bf_s(vals[j] * rms * nw0[j]);
    o[4 + j] = f2bf_s(vals[4 + j] * rms * nw1[j]);
  }
  *(s16x8*)((short*)ybf + base) = o;
}

// ---------------- launch ----------------
extern "C" void kernel_launch(void* const* d_in, const int* in_sizes, int n_in,
                              void* d_out, int out_size, void* d_ws, size_t ws_size,
                              hipStream_t stream) {
  const float* u       = (const float*)d_in[0];
  const float* W_in    = (const float*)d_in[1];
  const float* conv_w  = (const float*)d_in[2];
  const float* conv_b  = (const float*)d_in[3];
  const float* dt_bias = (const float*)d_in[4];
  const float* A_log   = (const float*)d_in[5];
  const float* Dp      = (const float*)d_in[6];
  const float* norm_w  = (const float*)d_in[7];
  const float* W_out   = (const float*)d_in[8];
  float* out = (float*)d_out;

  // --- workspace overlay (peak 148,176,896 bytes — proven layout) ---
  char* w = (char*)d_ws;
  const size_t OFF_WB   = 0;
  const size_t OFF_Z    = OFF_WB  + (size_t)DPROJ * DMODEL * 2;
  const size_t OFF_XBC  = OFF_Z   + (size_t)ROWS * DINNER * 2;
  const size_t OFF_DTR  = OFF_XBC + (size_t)ROWS * CONVDIM * 2;
  const size_t OFF_CONV = OFF_DTR + (size_t)ROWS * NHEADS * 4;
  const size_t OFF_CS   = OFF_CONV+ (size_t)ROWS * CONVDIM * 2;
  const size_t OFF_WOB  = OFF_WB;
  const size_t OFF_DSP  = OFF_WB + (size_t)DMODEL * DINNER * 2;
  const size_t OFF_CUM  = OFF_DSP + (size_t)ROWS * NHEADS * 4;

  __hip_bfloat16* Win_bf  = (__hip_bfloat16*)(w + OFF_WB);
  __hip_bfloat16* Wout_bf = (__hip_bfloat16*)(w + OFF_WOB);
  __hip_bfloat16* Bz      = (__hip_bfloat16*)(w + OFF_Z);
  __hip_bfloat16* Bx      = (__hip_bfloat16*)(w + OFF_XBC);
  float*          Bd      = (float*)(w + OFF_DTR);
  __hip_bfloat16* Bconv   = (__hip_bfloat16*)(w + OFF_CONV);
  float*          dt_sp   = (float*)(w + OFF_DSP);
  float*          cum     = (float*)(w + OFF_CUM);
  __hip_bfloat16* Bcs     = (__hip_bfloat16*)(w + OFF_CS);
  __hip_bfloat16* u_bf    = (__hip_bfloat16*)(w + OFF_CS);
  __hip_bfloat16* Yraw    = Bx;
  __hip_bfloat16* ybf     = Bcs;

  // 0. casts: W_in + u -> bf16 (one dispatch)
  {
    const int n1 = DPROJ * DMODEL, n2 = ROWS * DMODEL;
    cast2_f32_bf16<<<(n1 + n2) / 4 / 256, 256, 0, stream>>>(W_in, Win_bf, n1, u, u_bf, n2);
  }
  // 1. in-projection (256x128 tile, 512 thr): grid 32 x 34
  gemm_tiled<1><<<dim3(ROWS / 256, (DPROJ + 127) / 128), 512, 0, stream>>>(
      (const short*)u_bf, (const short*)Win_bf, Bz, Bx, Bd, nullptr, ROWS, DPROJ, DMODEL);
  // 0b. cast W_out -> bf16 (reuses Win_bf region)
  cast_f32_bf16<<<(DMODEL * DINNER / 4 + 255) / 256, 256, 0, stream>>>(W_out, Wout_bf, DMODEL * DINNER);
  // 2. conv + SiLU
  conv_silu_kernel<<<ROWS * 272 / 256, 256, 0, stream>>>(Bx, conv_w, conv_b, Bconv);
  // 3. dt softplus + cumsum (wave-parallel prefix scan)
  dt_cumsum_kernel<<<BSZ * NHEADS * NCHUNK / 4, 256, 0, stream>>>(
      Bd, dt_bias, A_log, dt_sp, cum);
  // 4. per-chunk states
  chunk_state_kernel<<<dim3(NCHUNK, NHEADS, BSZ), 256, 0, stream>>>(Bconv, dt_sp, cum, Bcs);
  // 5. inter-chunk exclusive scan
  scan_kernel<<<(BSZ * NHEADS * HEADDIM * DSTATE) / 256, 256, 0, stream>>>(Bcs, cum);
  // 6. Y
  y_kernel<<<dim3(NCHUNK, NHEADS, BSZ), 256, 0, stream>>>(Bconv, dt_sp, cum, Bcs, Dp, Yraw);
  // 7. gate + RMSNorm
  gate_norm_kernel<<<ROWS, 256, 0, stream>>>(Yraw, Bz, norm_w, ybf);
  // 8. out-projection: grid 32 x 8 = 256 blocks (1/CU exactly)
  gemm_tiled<0><<<dim3(ROWS / 256, DMODEL / 128), 512, 0, stream>>>(
      (const short*)ybf, (const short*)Wout_bf, nullptr, nullptr, nullptr, out, ROWS, DMODEL, DINNER);
}

// Round 4
// 384.733 us; speedup vs baseline: 1.0006x; 1.0006x over previous
//
#include <hip/hip_runtime.h>
#include <hip/hip_bf16.h>
#include <math.h>

// ---------------- constants ----------------
#define BSZ     2
#define TLEN    4096
#define DMODEL  1024
#define DINNER  2048
#define DSTATE  64
#define NHEADS  32
#define HEADDIM 64
#define CHUNK   64
#define NCHUNK  64            // TLEN / CHUNK
#define CONVDIM 2176          // DINNER + 2*DSTATE
#define DPROJ   4256          // 2*DINNER + 2*DSTATE + NHEADS
#define ROWS    8192          // BSZ*TLEN
#define LDP     72            // 64 + 8 pad (shorts) for MFMA LDS tiles
#define LDE     136           // 128 + 8 pad (shorts) for gemm epilogue tile

typedef __attribute__((ext_vector_type(8))) short s16x8;
typedef __attribute__((ext_vector_type(4))) short s16x4;
typedef __attribute__((ext_vector_type(4))) float f32x4;

__device__ __forceinline__ float bf2f(__hip_bfloat16 x) { return __bfloat162float(x); }
__device__ __forceinline__ __hip_bfloat16 f2bf(float x) { return __float2bfloat16(x); }
__device__ __forceinline__ short f2bf_s(float x) {
  union { __hip_bfloat16 h; short s; } c; c.h = __float2bfloat16(x); return c.s;
}
__device__ __forceinline__ float s2f(short s) {
  union { unsigned int u; float f; } c; c.u = ((unsigned int)(unsigned short)s) << 16; return c.f;
}
__device__ __forceinline__ s16x8 scale8(s16x8 a, float s) {
  s16x8 r;
#pragma unroll
  for (int i = 0; i < 8; ++i) r[i] = f2bf_s(s2f(a[i]) * s);
  return r;
}

#define GLDS16(g, l)                                                        \
  __builtin_amdgcn_global_load_lds(                                         \
      (const __attribute__((address_space(1))) void*)(g),                   \
      (__attribute__((address_space(3))) void*)(l), 16, 0, 0)

// fused counted-wait + barrier: nothing can be scheduled between them.
#define WAIT_BAR(N) asm volatile("s_waitcnt vmcnt(" #N ")\n\ts_barrier" ::: "memory")
// drain own ds_reads (data landed in VGPRs) then barrier: releases an LDS
// buffer for DMA overwrite with an airtight WAR edge.
#define LGKM_BAR    asm volatile("s_waitcnt lgkmcnt(0)\n\ts_barrier" ::: "memory")

// ---------------- f32 -> bf16 casts ----------------
__global__ __launch_bounds__(256) void cast_f32_bf16(
    const float* __restrict__ src, __hip_bfloat16* __restrict__ dst, int n) {
  const int i = (blockIdx.x * 256 + threadIdx.x) * 4;
  if (i + 3 < n) {
    const f32x4 v = *(const f32x4*)(src + i);
    dst[i + 0] = f2bf(v[0]); dst[i + 1] = f2bf(v[1]);
    dst[i + 2] = f2bf(v[2]); dst[i + 3] = f2bf(v[3]);
  } else {
    for (int j = i; j < n; ++j) dst[j] = f2bf(src[j]);
  }
}

__global__ __launch_bounds__(256) void cast2_f32_bf16(
    const float* __restrict__ s1, __hip_bfloat16* __restrict__ d1, int n1,
    const float* __restrict__ s2, __hip_bfloat16* __restrict__ d2, int n2) {
  const int i = (blockIdx.x * 256 + threadIdx.x) * 4;   // n1, n2 divisible by 4
  if (i < n1) {
    const f32x4 v = *(const f32x4*)(s1 + i);
    d1[i + 0] = f2bf(v[0]); d1[i + 1] = f2bf(v[1]);
    d1[i + 2] = f2bf(v[2]); d1[i + 3] = f2bf(v[3]);
  } else {
    const int j = i - n1;
    if (j < n2) {
      const f32x4 v = *(const f32x4*)(s2 + j);
      d2[j + 0] = f2bf(v[0]); d2[j + 1] = f2bf(v[1]);
      d2[j + 2] = f2bf(v[2]); d2[j + 3] = f2bf(v[3]);
    }
  }
}

// ---------------- LDS-tiled GEMM, BK=64, XOR-swizzled: C = A[M][K] @ B[N][K]^T ----------------
// r0-proven 128x128 tile, 4 waves (2Mx2N), 256 threads. r4 change (only):
// 2-deep LDS double-buffer (64 KB, still 2 blocks/CU) + counted vmcnt.
// Per K-tile: compute t from buf[t&1] -> LGKM_BAR (buffer released, WAR
// safe) -> STAGE t+2 into freed buffer (8 loads/wave) -> WAIT_BAR(8)
// (own t+1 loads done; after barrier ALL waves' t+1 done; t+2's 8 loads
// stay in flight across the whole next compute phase). Never vmcnt(0)
// in steady state -- removes r0's per-K-step full drain.
// SPLIT=1 (in-proj): operand-SWAPPED mfma -> acc regs hold 4 consecutive
//   output COLS; epilogue via LDS transpose tile -> 16B coalesced stores.
//   n-tiles 0-15 -> z (ld 2048), 16-32 -> xBC (ld 2176), 33 -> dt f32.
// SPLIT=0 (out-proj): unswapped, scalar coalesced f32 stores (K=2048).
template <int SPLIT>
__global__ __launch_bounds__(256) void gemm_tiled(
    const short* __restrict__ A, const short* __restrict__ B,
    __hip_bfloat16* __restrict__ Cz, __hip_bfloat16* __restrict__ Cx,
    float* __restrict__ Cd, float* __restrict__ Cout, int M, int N, int K) {
  // 2 x {A 128x64 | B 128x64} bf16 = 65536 B; epilogue tile (128*LDE*2 =
  // 34816 B) aliases buffer 0 after the final barrier.
  __shared__ __align__(16) short smem[4 * 8192];
  const int tid  = threadIdx.x;
  const int wave = tid >> 6, lane = tid & 63;
  const int lhi  = lane >> 4, llo = lane & 15;
  const int wm   = wave >> 1, wn = wave & 1;
  const int tm   = blockIdx.x * 128, tn = blockIdx.y * 128;

  // staging map: seg covers 8 rows (1 KB); lane i -> row seg*8 + i/8, global chunk (i&7)^(i>>3)
  const int srow = lane >> 3;                 // 0..7
  const int skc  = ((lane & 7) ^ srow) * 8;   // swizzled k-chunk (shorts)
  const int nk   = K >> 6;

  f32x4 acc[4][4];
  const f32x4 fz = {0.f, 0.f, 0.f, 0.f};
#pragma unroll
  for (int mi = 0; mi < 4; ++mi)
#pragma unroll
    for (int ni = 0; ni < 4; ++ni) acc[mi][ni] = fz;

  // per-wave: 4 A-chunks + 4 B-chunks of 1KB each -> 8 vmcnt events / K-tile
  auto STAGE = [&](int bi, int k0) {
    short* sA = smem + bi * 16384;
    short* sB = sA + 8192;
#pragma unroll
    for (int t = 0; t < 4; ++t) {
      const int seg = t * 4 + wave;                      // 0..15
      const int rl  = seg * 8 + srow;
      GLDS16(A + (size_t)(tm + rl) * K + k0 + skc, sA + seg * 512);
      GLDS16(B + (size_t)(tn + rl) * K + k0 + skc, sB + seg * 512);
    }
  };

  // prologue: tiles 0 and 1 staged; wait tile 0 only (tile 1 in flight)
  STAGE(0, 0);
  STAGE(1, 64);
  WAIT_BAR(8);

  for (int t = 0; t < nk; ++t) {
    const short* sA = smem + (t & 1) * 16384;
    const short* sB = sA + 8192;
#pragma unroll
    for (int sub = 0; sub < 2; ++sub) {
      s16x8 af[4], bfr[4];
#pragma unroll
      for (int i = 0; i < 4; ++i) {
        const int am = wm * 64 + i * 16 + llo;
        af[i]  = *(const s16x8*)(sA + am * 64 + ((sub * 4 + lhi) ^ (am & 7)) * 8);
        const int bn = wn * 64 + i * 16 + llo;
        bfr[i] = *(const s16x8*)(sB + bn * 64 + ((sub * 4 + lhi) ^ (bn & 7)) * 8);
      }
#pragma unroll
      for (int mi = 0; mi < 4; ++mi)
#pragma unroll
        for (int ni = 0; ni < 4; ++ni)
          acc[mi][ni] = SPLIT
            ? __builtin_amdgcn_mfma_f32_16x16x32_bf16(bfr[ni], af[mi], acc[mi][ni], 0, 0, 0)
            : __builtin_amdgcn_mfma_f32_16x16x32_bf16(af[mi], bfr[ni], acc[mi][ni], 0, 0, 0);
    }
    LGKM_BAR;                                  // all waves done reading buf[t&1]
    const bool pf = (t + 2 < nk);
    if (pf) {
      STAGE(t & 1, (t + 2) << 6);              // into the just-freed buffer
      WAIT_BAR(8);                             // t+1 resident; t+2 in flight
    } else {
      WAIT_BAR(0);                             // tail drain
    }
  }

  if (SPLIT) {
    // swapped layout: out_row = ...+llo, out_col = ...+lhi*4+r (4 consecutive cols per acc)
    if (blockIdx.y < 33) {
      // vectorized path via LDS transpose (region uniform per block)
#pragma unroll
      for (int mi = 0; mi < 4; ++mi)
#pragma unroll
        for (int ni = 0; ni < 4; ++ni) {
          const int rl = wm * 64 + mi * 16 + llo;
          const int cl = wn * 64 + ni * 16 + lhi * 4;
          s16x4 v;
#pragma unroll
          for (int r = 0; r < 4; ++r) v[r] = f2bf_s(acc[mi][ni][r]);
          *(s16x4*)(smem + rl * LDE + cl) = v;
        }
      __syncthreads();
      const int rl = tid >> 1;
      const int ch = (tid & 1) * 64;
      const short* src = smem + rl * LDE + ch;
      short* gp;
      if (blockIdx.y < 16)
        gp = (short*)Cz + (size_t)(tm + rl) * DINNER + tn + ch;
      else
        gp = (short*)Cx + (size_t)(tm + rl) * CONVDIM + (tn - DINNER) + ch;
#pragma unroll
      for (int j = 0; j < 8; ++j)
        *(s16x8*)(gp + j * 8) = *(const s16x8*)(src + j * 8);
    } else {
      // dt tile: cols 4224..4256 valid (local 0..32) -> f32, scalar
#pragma unroll
      for (int mi = 0; mi < 4; ++mi)
#pragma unroll
        for (int ni = 0; ni < 4; ++ni)
#pragma unroll
          for (int r = 0; r < 4; ++r) {
            const int col = wn * 64 + ni * 16 + lhi * 4 + r;
            if (col < NHEADS) {
              const int row = tm + wm * 64 + mi * 16 + llo;
              Cd[(size_t)row * NHEADS + col] = acc[mi][ni][r];
            }
          }
    }
  } else {
#pragma unroll
    for (int mi = 0; mi < 4; ++mi)
#pragma unroll
      for (int ni = 0; ni < 4; ++ni)
#pragma unroll
        for (int r = 0; r < 4; ++r) {
          const int row = tm + wm * 64 + mi * 16 + lhi * 4 + r;
          const int col = tn + wn * 64 + ni * 16 + llo;
          Cout[(size_t)row * N + col] = acc[mi][ni][r];
        }
  }
}

// ---------------- conv1d (depthwise, causal, width 4) + SiLU — vectorized 8 ch/thread ----------------
__global__ __launch_bounds__(256) void conv_silu_kernel(
    const __hip_bfloat16* __restrict__ xBC, const float* __restrict__ conv_w,
    const float* __restrict__ conv_b, __hip_bfloat16* __restrict__ convOut) {
  const int idx8 = blockIdx.x * 256 + threadIdx.x;   // bt*272 + c8
  const int c8 = idx8 % 272;
  const int bt = idx8 / 272;
  if (bt >= ROWS) return;
  const int t = bt & (TLEN - 1);
  const int c = c8 * 8;
  const short* xp = (const short*)xBC;

  f32x4 w4[8];
#pragma unroll
  for (int j = 0; j < 8; ++j) w4[j] = *(const f32x4*)(conv_w + (c + j) * 4);

  float acc[8];
  const f32x4 b0 = *(const f32x4*)(conv_b + c);
  const f32x4 b1 = *(const f32x4*)(conv_b + c + 4);
#pragma unroll
  for (int j = 0; j < 4; ++j) { acc[j] = b0[j]; acc[4 + j] = b1[j]; }

#pragma unroll
  for (int k = 0; k < 4; ++k) {
    const int tt = t - 3 + k;
    if (tt < 0) continue;
    const s16x8 xv = *(const s16x8*)(xp + (size_t)(bt - 3 + k) * CONVDIM + c);
#pragma unroll
    for (int j = 0; j < 8; ++j) acc[j] += w4[j][k] * s2f(xv[j]);
  }
  s16x8 o;
#pragma unroll
  for (int j = 0; j < 8; ++j) {
    const float s = acc[j] / (1.f + expf(-acc[j]));
    o[j] = f2bf_s(s);
  }
  *(s16x8*)((short*)convOut + (size_t)bt * CONVDIM + c) = o;
}

// ---------------- dt softplus + per-chunk cumsum of A*dt — one wave per (b,h,chunk) ----------------
__global__ __launch_bounds__(256) void dt_cumsum_kernel(
    const float* __restrict__ dt_raw, const float* __restrict__ dt_bias,
    const float* __restrict__ A_log, float* __restrict__ dt_sp, float* __restrict__ cum) {
  const int lane = threadIdx.x & 63;
  const int w = blockIdx.x * 4 + (threadIdx.x >> 6);   // bh*64 + c
  const int c = w & 63, bh = w >> 6;
  const int h = bh & 31, b = bh >> 5;
  const int t = c * CHUNK + lane;
  const float raw = dt_raw[((size_t)(b * TLEN + t)) * NHEADS + h] + dt_bias[h];
  const float d = (raw > 20.f) ? raw : log1pf(expf(raw));
  float v = -expf(A_log[h]) * d;
#pragma unroll
  for (int off = 1; off < 64; off <<= 1) {
    const float nb = __shfl_up(v, off, 64);
    if (lane >= off) v += nb;
  }
  dt_sp[(size_t)bh * TLEN + t] = d;
  cum[(size_t)bh * TLEN + t] = v;
}

// ---------------- per-chunk state (MFMA): cs[p][n] = sum_l xd[l][p]*B[l][n] ----------------
__global__ __launch_bounds__(256) void chunk_state_kernel(
    const __hip_bfloat16* __restrict__ convOut, const float* __restrict__ dt_sp,
    const float* __restrict__ cum, __hip_bfloat16* __restrict__ chunk_states) {
  __shared__ __align__(16) short sBT [64 * LDP];   // B^T [n][l]
  __shared__ __align__(16) short sXdT[64 * LDP];   // xd^T [p][l]
  const int c = blockIdx.x, h = blockIdx.y, b = blockIdx.z;
  const int tid = threadIdx.x;
  const int wave = tid >> 6, lane = tid & 63;
  const int lhi = lane >> 4, llo = lane & 15;
  const int bh = b * NHEADS + h;
  const float cumL = cum[(size_t)bh * TLEN + c * CHUNK + 63];
  const short* cOut = (const short*)convOut;

  for (int v = tid; v < 512; v += 256) {
    const int l = v >> 3, ch = v & 7;
    const size_t rowoff = ((size_t)(b * TLEN + c * CHUNK + l)) * CONVDIM;
    const s16x8 bv = *(const s16x8*)(cOut + rowoff + DINNER + ch * 8);
    const float wgt = dt_sp[(size_t)bh * TLEN + c * CHUNK + l] *
                      expf(cumL - cum[(size_t)bh * TLEN + c * CHUNK + l]);
    const s16x8 xv = *(const s16x8*)(cOut + rowoff + h * HEADDIM + ch * 8);
#pragma unroll
    for (int jj = 0; jj < 8; ++jj) {
      sBT [(ch * 8 + jj) * LDP + l] = bv[jj];
      sXdT[(ch * 8 + jj) * LDP + l] = f2bf_s(s2f(xv[jj]) * wgt);
    }
  }
  __syncthreads();

  const f32x4 fz = {0.f, 0.f, 0.f, 0.f};
  const s16x8 a0 = *(const s16x8*)(sXdT + (16 * wave + llo) * LDP + lhi * 8);
  const s16x8 a1 = *(const s16x8*)(sXdT + (16 * wave + llo) * LDP + 32 + lhi * 8);
  const size_t outb = ((((size_t)b * NCHUNK + c) * NHEADS + h) * HEADDIM) * DSTATE;
#pragma unroll
  for (int j = 0; j < 4; ++j) {
    const s16x8 b0 = *(const s16x8*)(sBT + (16 * j + llo) * LDP + lhi * 8);
    const s16x8 b1 = *(const s16x8*)(sBT + (16 * j + llo) * LDP + 32 + lhi * 8);
    f32x4 acc = fz;
    acc = __builtin_amdgcn_mfma_f32_16x16x32_bf16(a0, b0, acc, 0, 0, 0);
    acc = __builtin_amdgcn_mfma_f32_16x16x32_bf16(a1, b1, acc, 0, 0, 0);
#pragma unroll
    for (int r = 0; r < 4; ++r) {
      const int p = 16 * wave + lhi * 4 + r;
      const int n = 16 * j + llo;
      chunk_states[outb + (size_t)p * DSTATE + n] = f2bf(acc[r]);
    }
  }
}

// ---------------- inter-chunk scan, IN-PLACE ----------------
__global__ __launch_bounds__(256) void scan_kernel(
    __hip_bfloat16* __restrict__ cs, const float* __restrict__ cum) {
  const int idx = blockIdx.x * 256 + threadIdx.x;
  const int n = idx & 63;
  int r = idx >> 6;
  const int p = r & 63; r >>= 6;
  const int h = r & 31;
  const int b = r >> 5;
  const int bh = b * NHEADS + h;
  const size_t stride_c = (size_t)NHEADS * HEADDIM * DSTATE;
  const size_t base = ((size_t)b * NCHUNK) * stride_c + ((size_t)h * HEADDIM + p) * DSTATE + n;
  float s = 0.f;
  for (int c = 0; c < NCHUNK; ++c) {
    const size_t off = base + (size_t)c * stride_c;
    const float val = bf2f(cs[off]);
    cs[off] = f2bf(s);
    const float dec = expf(cum[(size_t)bh * TLEN + c * CHUNK + 63]);
    s = dec * s + val;
  }
}

// ---------------- per-chunk output (MFMA) ----------------
__global__ __launch_bounds__(256) void y_kernel(
    const __hip_bfloat16* __restrict__ convOut, const float* __restrict__ dt_sp,
    const float* __restrict__ cum, const __hip_bfloat16* __restrict__ states_pre,
    const float* __restrict__ Dparam, __hip_bfloat16* __restrict__ Yraw) {
  __shared__ __align__(16) short sC [64 * LDP];   // C[l][n]
  __shared__ __align__(16) short sBW[64 * LDP];   // phase1: B[s][n]; phase3: W[l][s]
  __shared__ __align__(16) short sXT[64 * LDP];   // xdt^T [p][s]
  __shared__ __align__(16) short sSP[64 * LDP];   // SP[p][n]
  __shared__ float scum[64];
  const int c = blockIdx.x, h = blockIdx.y, b = blockIdx.z;
  const int tid = threadIdx.x;
  const int wave = tid >> 6, lane = tid & 63;
  const int lhi = lane >> 4, llo = lane & 15;
  const int bh = b * NHEADS + h;
  const size_t tbase = (size_t)(b * TLEN + c * CHUNK);
  const short* cOut = (const short*)convOut;
  const size_t spbase = ((((size_t)b * NCHUNK + c) * NHEADS + h) * HEADDIM) * DSTATE;
  const f32x4 fz = {0.f, 0.f, 0.f, 0.f};

  for (int v = tid; v < 512; v += 256) {
    const int r = v >> 3, ch = v & 7;
    const size_t rowoff = (tbase + r) * CONVDIM;
    *(s16x8*)(sC  + r * LDP + ch * 8) = *(const s16x8*)(cOut + rowoff + DINNER + DSTATE + ch * 8);
    *(s16x8*)(sBW + r * LDP + ch * 8) = *(const s16x8*)(cOut + rowoff + DINNER + ch * 8);
    *(s16x8*)(sSP + r * LDP + ch * 8) = *(const s16x8*)((const short*)states_pre + spbase + r * 64 + ch * 8);
    const float dt = dt_sp[(size_t)bh * TLEN + c * CHUNK + r];
    const s16x8 xv = *(const s16x8*)(cOut + rowoff + h * HEADDIM + ch * 8);
#pragma unroll
    for (int jj = 0; jj < 8; ++jj)
      sXT[(ch * 8 + jj) * LDP + r] = f2bf_s(s2f(xv[jj]) * dt);
  }
  if (tid < 64) scum[tid] = cum[(size_t)bh * TLEN + c * CHUNK + tid];
  __syncthreads();

  // phase 1: G[l][s]
  const s16x8 aC0 = *(const s16x8*)(sC + (16 * wave + llo) * LDP + lhi * 8);
  const s16x8 aC1 = *(const s16x8*)(sC + (16 * wave + llo) * LDP + 32 + lhi * 8);
  f32x4 g[4];
#pragma unroll
  for (int j = 0; j < 4; ++j) {
    const s16x8 b0 = *(const s16x8*)(sBW + (16 * j + llo) * LDP + lhi * 8);
    const s16x8 b1 = *(const s16x8*)(sBW + (16 * j + llo) * LDP + 32 + lhi * 8);
    f32x4 acc = fz;
    acc = __builtin_amdgcn_mfma_f32_16x16x32_bf16(aC0, b0, acc, 0, 0, 0);
    acc = __builtin_amdgcn_mfma_f32_16x16x32_bf16(aC1, b1, acc, 0, 0, 0);
    g[j] = acc;
  }
  __syncthreads();

  // phase 2: W[l][s] = (s<=l) ? G*exp(cum[l]-cum[s]) : 0
  float cl[4];
#pragma unroll
  for (int r = 0; r < 4; ++r) cl[r] = scum[16 * wave + lhi * 4 + r];
#pragma unroll
  for (int j = 0; j < 4; ++j) {
    const int s = 16 * j + llo;
    const float cs_ = scum[s];
#pragma unroll
    for (int r = 0; r < 4; ++r) {
      const int l = 16 * wave + lhi * 4 + r;
      const float v = (s <= l) ? g[j][r] * expf(cl[r] - cs_) : 0.f;
      sBW[l * LDP + s] = f2bf_s(v);
    }
  }
  __syncthreads();

  // phase 3: Y[l][p]
  const float el = expf(scum[16 * wave + llo]);
  const s16x8 aCs0 = scale8(aC0, el);
  const s16x8 aCs1 = scale8(aC1, el);
  const s16x8 aW0 = *(const s16x8*)(sBW + (16 * wave + llo) * LDP + lhi * 8);
  const s16x8 aW1 = *(const s16x8*)(sBW + (16 * wave + llo) * LDP + 32 + lhi * 8);
  const float Dh = Dparam[h];
#pragma unroll
  for (int j = 0; j < 4; ++j) {
    const s16x8 bx0 = *(const s16x8*)(sXT + (16 * j + llo) * LDP + lhi * 8);
    const s16x8 bx1 = *(const s16x8*)(sXT + (16 * j + llo) * LDP + 32 + lhi * 8);
    const s16x8 bs0 = *(const s16x8*)(sSP + (16 * j + llo) * LDP + lhi * 8);
    const s16x8 bs1 = *(const s16x8*)(sSP + (16 * j + llo) * LDP + 32 + lhi * 8);
    f32x4 acc = fz;
    acc = __builtin_amdgcn_mfma_f32_16x16x32_bf16(aW0, bx0, acc, 0, 0, 0);
    acc = __builtin_amdgcn_mfma_f32_16x16x32_bf16(aW1, bx1, acc, 0, 0, 0);
    acc = __builtin_amdgcn_mfma_f32_16x16x32_bf16(aCs0, bs0, acc, 0, 0, 0);
    acc = __builtin_amdgcn_mfma_f32_16x16x32_bf16(aCs1, bs1, acc, 0, 0, 0);
#pragma unroll
    for (int r = 0; r < 4; ++r) {
      const int l = 16 * wave + lhi * 4 + r;
      const int p = 16 * j + llo;
      const size_t row = tbase + l;
      const float xval = bf2f(convOut[row * CONVDIM + h * HEADDIM + p]);
      Yraw[row * DINNER + h * HEADDIM + p] = f2bf(acc[r] + Dh * xval);
    }
  }
}

// ---------------- gate (silu(z)) + RMSNorm -> bf16 ----------------
__global__ __launch_bounds__(256) void gate_norm_kernel(
    const __hip_bfloat16* __restrict__ Yraw, const __hip_bfloat16* __restrict__ z,
    const float* __restrict__ norm_w, __hip_bfloat16* __restrict__ ybf) {
  const int row = blockIdx.x;
  const int tid = threadIdx.x;
  const size_t base = (size_t)row * DINNER + tid * 8;
  const s16x8 yv8 = *(const s16x8*)((const short*)Yraw + base);
  const s16x8 zv8 = *(const s16x8*)((const short*)z + base);
  float vals[8];
  float ss = 0.f;
#pragma unroll
  for (int j = 0; j < 8; ++j) {
    const float zv = s2f(zv8[j]);
    const float v = s2f(yv8[j]) * (zv / (1.f + expf(-zv)));
    vals[j] = v;
    ss += v * v;
  }
#pragma unroll
  for (int off = 32; off > 0; off >>= 1) ss += __shfl_down(ss, off, 64);
  __shared__ float red[4];
  if ((tid & 63) == 0) red[tid >> 6] = ss;
  __syncthreads();
  const float rms = rsqrtf((red[0] + red[1] + red[2] + red[3]) / (float)DINNER + 1e-5f);
  const f32x4 nw0 = *(const f32x4*)(norm_w + tid * 8);
  const f32x4 nw1 = *(const f32x4*)(norm_w + tid * 8 + 4);
  s16x8 o;
#pragma unroll
  for (int j = 0; j < 4; ++j) {
    o[j]     = f2bf_s(vals[j] * rms * nw0[j]);
    o[4 + j] = f2bf_s(vals[4 + j] * rms * nw1[j]);
  }
  *(s16x8*)((short*)ybf + base) = o;
}

// ---------------- launch ----------------
extern "C" void kernel_launch(void* const* d_in, const int* in_sizes, int n_in,
                              void* d_out, int out_size, void* d_ws, size_t ws_size,
                              hipStream_t stream) {
  const float* u       = (const float*)d_in[0];
  const float* W_in    = (const float*)d_in[1];
  const float* conv_w  = (const float*)d_in[2];
  const float* conv_b  = (const float*)d_in[3];
  const float* dt_bias = (const float*)d_in[4];
  const float* A_log   = (const float*)d_in[5];
  const float* Dp      = (const float*)d_in[6];
  const float* norm_w  = (const float*)d_in[7];
  const float* W_out   = (const float*)d_in[8];
  float* out = (float*)d_out;

  // --- workspace overlay (peak 148,176,896 bytes — proven layout) ---
  char* w = (char*)d_ws;
  const size_t OFF_WB   = 0;
  const size_t OFF_Z    = OFF_WB  + (size_t)DPROJ * DMODEL * 2;
  const size_t OFF_XBC  = OFF_Z   + (size_t)ROWS * DINNER * 2;
  const size_t OFF_DTR  = OFF_XBC + (size_t)ROWS * CONVDIM * 2;
  const size_t OFF_CONV = OFF_DTR + (size_t)ROWS * NHEADS * 4;
  const size_t OFF_CS   = OFF_CONV+ (size_t)ROWS * CONVDIM * 2;
  const size_t OFF_WOB  = OFF_WB;
  const size_t OFF_DSP  = OFF_WB + (size_t)DMODEL * DINNER * 2;
  const size_t OFF_CUM  = OFF_DSP + (size_t)ROWS * NHEADS * 4;

  __hip_bfloat16* Win_bf  = (__hip_bfloat16*)(w + OFF_WB);
  __hip_bfloat16* Wout_bf = (__hip_bfloat16*)(w + OFF_WOB);
  __hip_bfloat16* Bz      = (__hip_bfloat16*)(w + OFF_Z);
  __hip_bfloat16* Bx      = (__hip_bfloat16*)(w + OFF_XBC);
  float*          Bd      = (float*)(w + OFF_DTR);
  __hip_bfloat16* Bconv   = (__hip_bfloat16*)(w + OFF_CONV);
  float*          dt_sp   = (float*)(w + OFF_DSP);
  float*          cum     = (float*)(w + OFF_CUM);
  __hip_bfloat16* Bcs     = (__hip_bfloat16*)(w + OFF_CS);
  __hip_bfloat16* u_bf    = (__hip_bfloat16*)(w + OFF_CS);
  __hip_bfloat16* Yraw    = Bx;
  __hip_bfloat16* ybf     = Bcs;

  // 0. casts: W_in + u -> bf16 (one dispatch)
  {
    const int n1 = DPROJ * DMODEL, n2 = ROWS * DMODEL;
    cast2_f32_bf16<<<(n1 + n2) / 4 / 256, 256, 0, stream>>>(W_in, Win_bf, n1, u, u_bf, n2);
  }
  // 1. in-projection
  gemm_tiled<1><<<dim3(ROWS / 128, (DPROJ + 127) / 128), 256, 0, stream>>>(
      (const short*)u_bf, (const short*)Win_bf, Bz, Bx, Bd, nullptr, ROWS, DPROJ, DMODEL);
  // 0b. cast W_out -> bf16 (reuses Win_bf region)
  cast_f32_bf16<<<(DMODEL * DINNER / 4 + 255) / 256, 256, 0, stream>>>(W_out, Wout_bf, DMODEL * DINNER);
  // 2. conv + SiLU
  conv_silu_kernel<<<ROWS * 272 / 256, 256, 0, stream>>>(Bx, conv_w, conv_b, Bconv);
  // 3. dt softplus + cumsum (wave-parallel prefix scan)
  dt_cumsum_kernel<<<BSZ * NHEADS * NCHUNK / 4, 256, 0, stream>>>(
      Bd, dt_bias, A_log, dt_sp, cum);
  // 4. per-chunk states
  chunk_state_kernel<<<dim3(NCHUNK, NHEADS, BSZ), 256, 0, stream>>>(Bconv, dt_sp, cum, Bcs);
  // 5. inter-chunk exclusive scan
  scan_kernel<<<(BSZ * NHEADS * HEADDIM * DSTATE) / 256, 256, 0, stream>>>(Bcs, cum);
  // 6. Y
  y_kernel<<<dim3(NCHUNK, NHEADS, BSZ), 256, 0, stream>>>(Bconv, dt_sp, cum, Bcs, Dp, Yraw);
  // 7. gate + RMSNorm
  gate_norm_kernel<<<ROWS, 256, 0, stream>>>(Yraw, Bz, norm_w, ybf);
  // 8. out-projection
  gemm_tiled<0><<<dim3(ROWS / 128, DMODEL / 128), 256, 0, stream>>>(
      (const short*)ybf, (const short*)Wout_bf, nullptr, nullptr, nullptr, out, ROWS, DMODEL, DINNER);
}

// Round 5
// 379.986 us; speedup vs baseline: 1.0131x; 1.0125x over previous
//
#include <hip/hip_runtime.h>
#include <hip/hip_bf16.h>
#include <math.h>

// ---------------- constants ----------------
#define BSZ     2
#define TLEN    4096
#define DMODEL  1024
#define DINNER  2048
#define DSTATE  64
#define NHEADS  32
#define HEADDIM 64
#define CHUNK   64
#define NCHUNK  64            // TLEN / CHUNK
#define CONVDIM 2176          // DINNER + 2*DSTATE
#define DPROJ   4256          // 2*DINNER + 2*DSTATE + NHEADS
#define ROWS    8192          // BSZ*TLEN
#define LDP     72            // 64 + 8 pad (shorts) for MFMA LDS tiles
#define LDE     136           // 128 + 8 pad (shorts) for 128-wide epilogue tile
#define LDE2    264           // 256 + 8 pad (shorts) for 256-wide epilogue tile

typedef __attribute__((ext_vector_type(8))) short s16x8;
typedef __attribute__((ext_vector_type(4))) short s16x4;
typedef __attribute__((ext_vector_type(4))) float f32x4;

__device__ __forceinline__ float bf2f(__hip_bfloat16 x) { return __bfloat162float(x); }
__device__ __forceinline__ __hip_bfloat16 f2bf(float x) { return __float2bfloat16(x); }
__device__ __forceinline__ short f2bf_s(float x) {
  union { __hip_bfloat16 h; short s; } c; c.h = __float2bfloat16(x); return c.s;
}
__device__ __forceinline__ float s2f(short s) {
  union { unsigned int u; float f; } c; c.u = ((unsigned int)(unsigned short)s) << 16; return c.f;
}
__device__ __forceinline__ s16x8 scale8(s16x8 a, float s) {
  s16x8 r;
#pragma unroll
  for (int i = 0; i < 8; ++i) r[i] = f2bf_s(s2f(a[i]) * s);
  return r;
}

#define GLDS16(g, l)                                                        \
  __builtin_amdgcn_global_load_lds(                                         \
      (const __attribute__((address_space(1))) void*)(g),                   \
      (__attribute__((address_space(3))) void*)(l), 16, 0, 0)

// fused waits+barrier: single asm statements so nothing schedules between.
#define BARRIER       asm volatile("s_barrier" ::: "memory")
#define WAIT_BAR(N)   asm volatile("s_waitcnt vmcnt(" #N ")\n\ts_barrier" ::: "memory")
#define LGKM_BAR      asm volatile("s_waitcnt lgkmcnt(0)\n\ts_barrier" ::: "memory")
#define LGVM_BAR(N)   asm volatile("s_waitcnt lgkmcnt(0) vmcnt(" #N ")\n\ts_barrier" ::: "memory")

// ---------------- f32 -> bf16 casts ----------------
__global__ __launch_bounds__(256) void cast_f32_bf16(
    const float* __restrict__ src, __hip_bfloat16* __restrict__ dst, int n) {
  const int i = (blockIdx.x * 256 + threadIdx.x) * 4;
  if (i + 3 < n) {
    const f32x4 v = *(const f32x4*)(src + i);
    dst[i + 0] = f2bf(v[0]); dst[i + 1] = f2bf(v[1]);
    dst[i + 2] = f2bf(v[2]); dst[i + 3] = f2bf(v[3]);
  } else {
    for (int j = i; j < n; ++j) dst[j] = f2bf(src[j]);
  }
}

__global__ __launch_bounds__(256) void cast2_f32_bf16(
    const float* __restrict__ s1, __hip_bfloat16* __restrict__ d1, int n1,
    const float* __restrict__ s2, __hip_bfloat16* __restrict__ d2, int n2) {
  const int i = (blockIdx.x * 256 + threadIdx.x) * 4;   // n1, n2 divisible by 4
  if (i < n1) {
    const f32x4 v = *(const f32x4*)(s1 + i);
    d1[i + 0] = f2bf(v[0]); d1[i + 1] = f2bf(v[1]);
    d1[i + 2] = f2bf(v[2]); d1[i + 3] = f2bf(v[3]);
  } else {
    const int j = i - n1;
    if (j < n2) {
      const f32x4 v = *(const f32x4*)(s2 + j);
      d2[j + 0] = f2bf(v[0]); d2[j + 1] = f2bf(v[1]);
      d2[j + 2] = f2bf(v[2]); d2[j + 3] = f2bf(v[3]);
    }
  }
}

// ---------------- r0-proven LDS-tiled GEMM (out-proj): C = A[M][K] @ B[N][K]^T ----------------
// 128x128 tile, 4 waves each 64x64, single-buffered, 34.8 KB LDS -> 4 blocks/CU.
template <int SPLIT>
__global__ __launch_bounds__(256) void gemm_tiled(
    const short* __restrict__ A, const short* __restrict__ B,
    __hip_bfloat16* __restrict__ Cz, __hip_bfloat16* __restrict__ Cx,
    float* __restrict__ Cd, float* __restrict__ Cout, int M, int N, int K) {
  __shared__ __align__(16) short smem[128 * LDE];   // 34.8 KB; staging aliases epilogue tile
  short* sA = smem;                                  // 128*64
  short* sB = smem + 128 * 64;                       // 128*64
  const int tid  = threadIdx.x;
  const int wave = tid >> 6, lane = tid & 63;
  const int lhi  = lane >> 4, llo = lane & 15;
  const int wm   = wave >> 1, wn = wave & 1;
  const int tm   = blockIdx.x * 128, tn = blockIdx.y * 128;

  const int srow = lane >> 3;                 // 0..7
  const int skc  = ((lane & 7) ^ srow) * 8;   // swizzled k-chunk (shorts)

  f32x4 acc[4][4];
  const f32x4 fz = {0.f, 0.f, 0.f, 0.f};
#pragma unroll
  for (int mi = 0; mi < 4; ++mi)
#pragma unroll
    for (int ni = 0; ni < 4; ++ni) acc[mi][ni] = fz;

  for (int k0 = 0; k0 < K; k0 += 64) {
#pragma unroll
    for (int t = 0; t < 4; ++t) {
      const int seg = t * 4 + wave;                      // 0..15
      const int rl  = seg * 8 + srow;
      GLDS16(A + (size_t)(tm + rl) * K + k0 + skc, sA + seg * 512);
      GLDS16(B + (size_t)(tn + rl) * K + k0 + skc, sB + seg * 512);
    }
    __syncthreads();
#pragma unroll
    for (int sub = 0; sub < 2; ++sub) {
      s16x8 af[4], bfr[4];
#pragma unroll
      for (int i = 0; i < 4; ++i) {
        const int am = wm * 64 + i * 16 + llo;
        af[i]  = *(const s16x8*)(sA + am * 64 + ((sub * 4 + lhi) ^ (am & 7)) * 8);
        const int bn = wn * 64 + i * 16 + llo;
        bfr[i] = *(const s16x8*)(sB + bn * 64 + ((sub * 4 + lhi) ^ (bn & 7)) * 8);
      }
#pragma unroll
      for (int mi = 0; mi < 4; ++mi)
#pragma unroll
        for (int ni = 0; ni < 4; ++ni)
          acc[mi][ni] = SPLIT
            ? __builtin_amdgcn_mfma_f32_16x16x32_bf16(bfr[ni], af[mi], acc[mi][ni], 0, 0, 0)
            : __builtin_amdgcn_mfma_f32_16x16x32_bf16(af[mi], bfr[ni], acc[mi][ni], 0, 0, 0);
    }
    __syncthreads();
  }

  if (SPLIT) {
    if (blockIdx.y < 33) {
#pragma unroll
      for (int mi = 0; mi < 4; ++mi)
#pragma unroll
        for (int ni = 0; ni < 4; ++ni) {
          const int rl = wm * 64 + mi * 16 + llo;
          const int cl = wn * 64 + ni * 16 + lhi * 4;
          s16x4 v;
#pragma unroll
          for (int r = 0; r < 4; ++r) v[r] = f2bf_s(acc[mi][ni][r]);
          *(s16x4*)(smem + rl * LDE + cl) = v;
        }
      __syncthreads();
      const int rl = tid >> 1;
      const int ch = (tid & 1) * 64;
      const short* src = smem + rl * LDE + ch;
      short* gp;
      if (blockIdx.y < 16)
        gp = (short*)Cz + (size_t)(tm + rl) * DINNER + tn + ch;
      else
        gp = (short*)Cx + (size_t)(tm + rl) * CONVDIM + (tn - DINNER) + ch;
#pragma unroll
      for (int j = 0; j < 8; ++j)
        *(s16x8*)(gp + j * 8) = *(const s16x8*)(src + j * 8);
    } else {
#pragma unroll
      for (int mi = 0; mi < 4; ++mi)
#pragma unroll
        for (int ni = 0; ni < 4; ++ni)
#pragma unroll
          for (int r = 0; r < 4; ++r) {
            const int col = wn * 64 + ni * 16 + lhi * 4 + r;
            if (col < NHEADS) {
              const int row = tm + wm * 64 + mi * 16 + llo;
              Cd[(size_t)row * NHEADS + col] = acc[mi][ni][r];
            }
          }
    }
  } else {
#pragma unroll
    for (int mi = 0; mi < 4; ++mi)
#pragma unroll
      for (int ni = 0; ni < 4; ++ni)
#pragma unroll
        for (int r = 0; r < 4; ++r) {
          const int row = tm + wm * 64 + mi * 16 + lhi * 4 + r;
          const int col = tn + wn * 64 + ni * 16 + llo;
          Cout[(size_t)row * N + col] = acc[mi][ni][r];
        }
  }
}

// ---------------- 8-phase pipelined in-proj GEMM (m201/m248 schedule, plain HIP) ----------------
// BM=128 x BN=256, BK=64, 8 waves (2M x 4N, 64x64 each), 2 K-tiles/iter,
// 8 phases/iter: { 8 ds_read_b128 (one k-slice) || 1 stage event ->
// s_barrier -> setprio(1) + 8 MFMA + setprio(0) -> lgkmcnt(0)-fused barrier }.
// LDS = 2 buf x { A 128x64 | B 256x64 } = 96 KB (1 block/CU; pipeline replaces TLP).
// Stage events (1..2 global_load_lds): ph1,2 = tile(2i+1) B-halves (completing
// buf1); ph3,4 = tile(2i+2) A-halves; ph5,6 = tile(2i+2) B-halves (buf0 freed
// by ph2's lgkm-drained barrier); ph7,8 = tile(2i+3) A-halves (buf1 freed ph6).
// WAR: every region's last ds_reads are issued+drained (lgkmcnt(0) in closing
// barrier) >=1 barrier before its restage; the lgkm drain also closes the
// ds_read-queue vs DMA-landing order hole. RAW: vmcnt(2) at ph4 (oldest-6 =
// tile 2i+1 complete before ph5 reads) and ph8 (oldest-6 = tile 2i+2 complete
// before next ph1). Never vmcnt(0) in steady state.
__global__ __launch_bounds__(512, 2) void gemm_8ph_inproj(
    const short* __restrict__ A, const short* __restrict__ B,
    __hip_bfloat16* __restrict__ Cz, __hip_bfloat16* __restrict__ Cx,
    float* __restrict__ Cd, int K) {
  __shared__ __align__(16) short smem[2 * 24576];   // 96 KB
  const int tid  = threadIdx.x;
  const int wave = tid >> 6, lane = tid & 63;
  const int lhi  = lane >> 4, llo = lane & 15;
  const int wm   = wave >> 2, wn = wave & 3;        // 2M x 4N
  const int tm   = blockIdx.x * 128, tn = blockIdx.y * 256;
  const int srow = lane >> 3;
  const int skc  = ((lane & 7) ^ srow) * 8;
  const int iters = K >> 7;                         // 2 K-tiles / iter

  f32x4 acc[4][4];
  const f32x4 fz = {0.f, 0.f, 0.f, 0.f};
#pragma unroll
  for (int m = 0; m < 4; ++m)
#pragma unroll
    for (int n = 0; n < 4; ++n) acc[m][n] = fz;

  // stage: A-half h (64 rows, 1 load/thread), B-half h (128 rows, 2 loads)
  auto ST_A = [&](int bi, int k0, int h) {
    short* bA = smem + bi * 24576;
    const int rl = h * 64 + wave * 8 + srow;
    GLDS16(A + (size_t)(tm + rl) * K + k0 + skc, bA + (h * 8 + wave) * 512);
  };
  auto ST_B = [&](int bi, int k0, int h) {
    short* bB = smem + bi * 24576 + 8192;
#pragma unroll
    for (int i = 0; i < 2; ++i) {
      const int ck = i * 8 + wave;
      const int rl = h * 128 + ck * 8 + srow;
      GLDS16(B + (size_t)(tn + rl) * K + k0 + skc, bB + (h * 16 + ck) * 512);
    }
  };

#define RD_FRAGS(bufA, bufB, kk, AF, BF)                                      \
  {                                                                           \
    _Pragma("unroll")                                                         \
    for (int m_ = 0; m_ < 4; ++m_) {                                          \
      const int am_ = wm * 64 + m_ * 16 + llo;                                \
      AF[m_] = *(const s16x8*)((bufA) + am_ * 64 +                            \
                               ((((kk) << 2) + lhi) ^ (am_ & 7)) * 8);        \
    }                                                                         \
    _Pragma("unroll")                                                         \
    for (int n_ = 0; n_ < 4; ++n_) {                                          \
      const int bn_ = wn * 64 + n_ * 16 + llo;                                \
      BF[n_] = *(const s16x8*)((bufB) + bn_ * 64 +                            \
                               ((((kk) << 2) + lhi) ^ (bn_ & 7)) * 8);        \
    }                                                                         \
  }

#define MF8(AF, BF, N0, N1)                                                   \
  {                                                                           \
    __builtin_amdgcn_s_setprio(1);                                            \
    _Pragma("unroll")                                                         \
    for (int m_ = 0; m_ < 4; ++m_) {                                          \
      acc[m_][N0] = __builtin_amdgcn_mfma_f32_16x16x32_bf16(                  \
          BF[N0], AF[m_], acc[m_][N0], 0, 0, 0);                              \
      acc[m_][N1] = __builtin_amdgcn_mfma_f32_16x16x32_bf16(                  \
          BF[N1], AF[m_], acc[m_][N1], 0, 0, 0);                              \
    }                                                                         \
    __builtin_amdgcn_s_setprio(0);                                            \
  }

  // prologue: tile0 complete (6 loads) + tile1 A-halves (2) -> vmcnt(2)
  ST_A(0, 0, 0); ST_A(0, 0, 1); ST_B(0, 0, 0); ST_B(0, 0, 1);
  ST_A(1, 64, 0); ST_A(1, 64, 1);
  WAIT_BAR(2);

  for (int it = 0; it < iters; ++it) {
    const short* b0A = smem;            const short* b0B = smem + 8192;
    const short* b1A = smem + 24576;    const short* b1B = smem + 24576 + 8192;
    const bool last = (it == iters - 1);
    const int kt1 = (2 * it + 1) << 6;
    const int kt2 = (2 * it + 2) << 6;
    const int kt3 = (2 * it + 3) << 6;
    s16x8 a0[4], a1[4], b0v[4], b1v[4];

    // ph1
    RD_FRAGS(b0A, b0B, 0, a0, b0v);
    ST_B(1, kt1, 0);
    BARRIER;  MF8(a0, b0v, 0, 1);  LGKM_BAR;
    // ph2
    RD_FRAGS(b0A, b0B, 1, a1, b1v);
    ST_B(1, kt1, 1);
    BARRIER;  MF8(a0, b0v, 2, 3);  LGKM_BAR;
    // ph3
    if (!last) ST_A(0, kt2, 0);
    BARRIER;  MF8(a1, b1v, 0, 1);  LGKM_BAR;
    // ph4
    if (!last) ST_A(0, kt2, 1);
    BARRIER;  MF8(a1, b1v, 2, 3);
    if (!last) { LGVM_BAR(2); } else { LGVM_BAR(0); }
    // ph5
    RD_FRAGS(b1A, b1B, 0, a0, b0v);
    if (!last) ST_B(0, kt2, 0);
    BARRIER;  MF8(a0, b0v, 0, 1);  LGKM_BAR;
    // ph6
    RD_FRAGS(b1A, b1B, 1, a1, b1v);
    if (!last) ST_B(0, kt2, 1);
    BARRIER;  MF8(a0, b0v, 2, 3);  LGKM_BAR;
    // ph7
    if (!last) ST_A(1, kt3, 0);
    BARRIER;  MF8(a1, b1v, 0, 1);  LGKM_BAR;
    // ph8
    if (!last) ST_A(1, kt3, 1);
    BARRIER;  MF8(a1, b1v, 2, 3);
    if (!last) { LGVM_BAR(2); } else { LGVM_BAR(0); }
  }
#undef RD_FRAGS
#undef MF8

  // ---- epilogue (swapped layout: row = +llo, col = +lhi*4+r) ----
  // dt scalar path from acc registers (block y=16, cols 4224..4255 -> f32)
  if (blockIdx.y == 16) {
#pragma unroll
    for (int m = 0; m < 4; ++m)
#pragma unroll
      for (int n = 0; n < 4; ++n)
#pragma unroll
        for (int r = 0; r < 4; ++r) {
          const int gcol = tn + wn * 64 + n * 16 + lhi * 4 + r;
          if (gcol >= 4224 && gcol < DPROJ) {
            const int grow = tm + wm * 64 + m * 16 + llo;
            Cd[(size_t)grow * NHEADS + (gcol - 4224)] = acc[m][n][r];
          }
        }
  }
  // vectorized z / xBC path via LDS transpose tile [128][LDE2]
#pragma unroll
  for (int m = 0; m < 4; ++m)
#pragma unroll
    for (int n = 0; n < 4; ++n) {
      const int rl = wm * 64 + m * 16 + llo;
      const int cl = wn * 64 + n * 16 + lhi * 4;
      s16x4 v;
#pragma unroll
      for (int r = 0; r < 4; ++r) v[r] = f2bf_s(acc[m][n][r]);
      *(s16x4*)(smem + rl * LDE2 + cl) = v;
    }
  __syncthreads();
  {
    const int rl = tid >> 2;                 // 0..127
    const int ch = (tid & 3) * 64;           // 64-col chunk
    const int gcol0 = tn + ch;
    const short* src = smem + rl * LDE2 + ch;
    short* gp = nullptr;
    if (gcol0 < DINNER)
      gp = (short*)Cz + (size_t)(tm + rl) * DINNER + gcol0;
    else if (gcol0 < 4224)
      gp = (short*)Cx + (size_t)(tm + rl) * CONVDIM + (gcol0 - DINNER);
    if (gp) {
#pragma unroll
      for (int j = 0; j < 8; ++j)
        *(s16x8*)(gp + j * 8) = *(const s16x8*)(src + j * 8);
    }
  }
}

// ---------------- conv1d (depthwise, causal, width 4) + SiLU — vectorized 8 ch/thread ----------------
__global__ __launch_bounds__(256) void conv_silu_kernel(
    const __hip_bfloat16* __restrict__ xBC, const float* __restrict__ conv_w,
    const float* __restrict__ conv_b, __hip_bfloat16* __restrict__ convOut) {
  const int idx8 = blockIdx.x * 256 + threadIdx.x;   // bt*272 + c8
  const int c8 = idx8 % 272;
  const int bt = idx8 / 272;
  if (bt >= ROWS) return;
  const int t = bt & (TLEN - 1);
  const int c = c8 * 8;
  const short* xp = (const short*)xBC;

  f32x4 w4[8];
#pragma unroll
  for (int j = 0; j < 8; ++j) w4[j] = *(const f32x4*)(conv_w + (c + j) * 4);

  float acc[8];
  const f32x4 b0 = *(const f32x4*)(conv_b + c);
  const f32x4 b1 = *(const f32x4*)(conv_b + c + 4);
#pragma unroll
  for (int j = 0; j < 4; ++j) { acc[j] = b0[j]; acc[4 + j] = b1[j]; }

#pragma unroll
  for (int k = 0; k < 4; ++k) {
    const int tt = t - 3 + k;
    if (tt < 0) continue;
    const s16x8 xv = *(const s16x8*)(xp + (size_t)(bt - 3 + k) * CONVDIM + c);
#pragma unroll
    for (int j = 0; j < 8; ++j) acc[j] += w4[j][k] * s2f(xv[j]);
  }
  s16x8 o;
#pragma unroll
  for (int j = 0; j < 8; ++j) {
    const float s = acc[j] / (1.f + expf(-acc[j]));
    o[j] = f2bf_s(s);
  }
  *(s16x8*)((short*)convOut + (size_t)bt * CONVDIM + c) = o;
}

// ---------------- dt softplus + per-chunk cumsum of A*dt — one wave per (b,h,chunk) ----------------
__global__ __launch_bounds__(256) void dt_cumsum_kernel(
    const float* __restrict__ dt_raw, const float* __restrict__ dt_bias,
    const float* __restrict__ A_log, float* __restrict__ dt_sp, float* __restrict__ cum) {
  const int lane = threadIdx.x & 63;
  const int w = blockIdx.x * 4 + (threadIdx.x >> 6);   // bh*64 + c
  const int c = w & 63, bh = w >> 6;
  const int h = bh & 31, b = bh >> 5;
  const int t = c * CHUNK + lane;
  const float raw = dt_raw[((size_t)(b * TLEN + t)) * NHEADS + h] + dt_bias[h];
  const float d = (raw > 20.f) ? raw : log1pf(expf(raw));
  float v = -expf(A_log[h]) * d;
#pragma unroll
  for (int off = 1; off < 64; off <<= 1) {
    const float nb = __shfl_up(v, off, 64);
    if (lane >= off) v += nb;
  }
  dt_sp[(size_t)bh * TLEN + t] = d;
  cum[(size_t)bh * TLEN + t] = v;
}

// ---------------- per-chunk state (MFMA): cs[p][n] = sum_l xd[l][p]*B[l][n] ----------------
__global__ __launch_bounds__(256) void chunk_state_kernel(
    const __hip_bfloat16* __restrict__ convOut, const float* __restrict__ dt_sp,
    const float* __restrict__ cum, __hip_bfloat16* __restrict__ chunk_states) {
  __shared__ __align__(16) short sBT [64 * LDP];   // B^T [n][l]
  __shared__ __align__(16) short sXdT[64 * LDP];   // xd^T [p][l]
  const int c = blockIdx.x, h = blockIdx.y, b = blockIdx.z;
  const int tid = threadIdx.x;
  const int wave = tid >> 6, lane = tid & 63;
  const int lhi = lane >> 4, llo = lane & 15;
  const int bh = b * NHEADS + h;
  const float cumL = cum[(size_t)bh * TLEN + c * CHUNK + 63];
  const short* cOut = (const short*)convOut;

  for (int v = tid; v < 512; v += 256) {
    const int l = v >> 3, ch = v & 7;
    const size_t rowoff = ((size_t)(b * TLEN + c * CHUNK + l)) * CONVDIM;
    const s16x8 bv = *(const s16x8*)(cOut + rowoff + DINNER + ch * 8);
    const float wgt = dt_sp[(size_t)bh * TLEN + c * CHUNK + l] *
                      expf(cumL - cum[(size_t)bh * TLEN + c * CHUNK + l]);
    const s16x8 xv = *(const s16x8*)(cOut + rowoff + h * HEADDIM + ch * 8);
#pragma unroll
    for (int jj = 0; jj < 8; ++jj) {
      sBT [(ch * 8 + jj) * LDP + l] = bv[jj];
      sXdT[(ch * 8 + jj) * LDP + l] = f2bf_s(s2f(xv[jj]) * wgt);
    }
  }
  __syncthreads();

  const f32x4 fz = {0.f, 0.f, 0.f, 0.f};
  const s16x8 a0 = *(const s16x8*)(sXdT + (16 * wave + llo) * LDP + lhi * 8);
  const s16x8 a1 = *(const s16x8*)(sXdT + (16 * wave + llo) * LDP + 32 + lhi * 8);
  const size_t outb = ((((size_t)b * NCHUNK + c) * NHEADS + h) * HEADDIM) * DSTATE;
#pragma unroll
  for (int j = 0; j < 4; ++j) {
    const s16x8 b0 = *(const s16x8*)(sBT + (16 * j + llo) * LDP + lhi * 8);
    const s16x8 b1 = *(const s16x8*)(sBT + (16 * j + llo) * LDP + 32 + lhi * 8);
    f32x4 acc = fz;
    acc = __builtin_amdgcn_mfma_f32_16x16x32_bf16(a0, b0, acc, 0, 0, 0);
    acc = __builtin_amdgcn_mfma_f32_16x16x32_bf16(a1, b1, acc, 0, 0, 0);
#pragma unroll
    for (int r = 0; r < 4; ++r) {
      const int p = 16 * wave + lhi * 4 + r;
      const int n = 16 * j + llo;
      chunk_states[outb + (size_t)p * DSTATE + n] = f2bf(acc[r]);
    }
  }
}

// ---------------- inter-chunk scan, IN-PLACE ----------------
__global__ __launch_bounds__(256) void scan_kernel(
    __hip_bfloat16* __restrict__ cs, const float* __restrict__ cum) {
  const int idx = blockIdx.x * 256 + threadIdx.x;
  const int n = idx & 63;
  int r = idx >> 6;
  const int p = r & 63; r >>= 6;
  const int h = r & 31;
  const int b = r >> 5;
  const int bh = b * NHEADS + h;
  const size_t stride_c = (size_t)NHEADS * HEADDIM * DSTATE;
  const size_t base = ((size_t)b * NCHUNK) * stride_c + ((size_t)h * HEADDIM + p) * DSTATE + n;
  float s = 0.f;
  for (int c = 0; c < NCHUNK; ++c) {
    const size_t off = base + (size_t)c * stride_c;
    const float val = bf2f(cs[off]);
    cs[off] = f2bf(s);
    const float dec = expf(cum[(size_t)bh * TLEN + c * CHUNK + 63]);
    s = dec * s + val;
  }
}

// ---------------- per-chunk output (MFMA) ----------------
__global__ __launch_bounds__(256) void y_kernel(
    const __hip_bfloat16* __restrict__ convOut, const float* __restrict__ dt_sp,
    const float* __restrict__ cum, const __hip_bfloat16* __restrict__ states_pre,
    const float* __restrict__ Dparam, __hip_bfloat16* __restrict__ Yraw) {
  __shared__ __align__(16) short sC [64 * LDP];   // C[l][n]
  __shared__ __align__(16) short sBW[64 * LDP];   // phase1: B[s][n]; phase3: W[l][s]
  __shared__ __align__(16) short sXT[64 * LDP];   // xdt^T [p][s]
  __shared__ __align__(16) short sSP[64 * LDP];   // SP[p][n]
  __shared__ float scum[64];
  const int c = blockIdx.x, h = blockIdx.y, b = blockIdx.z;
  const int tid = threadIdx.x;
  const int wave = tid >> 6, lane = tid & 63;
  const int lhi = lane >> 4, llo = lane & 15;
  const int bh = b * NHEADS + h;
  const size_t tbase = (size_t)(b * TLEN + c * CHUNK);
  const short* cOut = (const short*)convOut;
  const size_t spbase = ((((size_t)b * NCHUNK + c) * NHEADS + h) * HEADDIM) * DSTATE;
  const f32x4 fz = {0.f, 0.f, 0.f, 0.f};

  for (int v = tid; v < 512; v += 256) {
    const int r = v >> 3, ch = v & 7;
    const size_t rowoff = (tbase + r) * CONVDIM;
    *(s16x8*)(sC  + r * LDP + ch * 8) = *(const s16x8*)(cOut + rowoff + DINNER + DSTATE + ch * 8);
    *(s16x8*)(sBW + r * LDP + ch * 8) = *(const s16x8*)(cOut + rowoff + DINNER + ch * 8);
    *(s16x8*)(sSP + r * LDP + ch * 8) = *(const s16x8*)((const short*)states_pre + spbase + r * 64 + ch * 8);
    const float dt = dt_sp[(size_t)bh * TLEN + c * CHUNK + r];
    const s16x8 xv = *(const s16x8*)(cOut + rowoff + h * HEADDIM + ch * 8);
#pragma unroll
    for (int jj = 0; jj < 8; ++jj)
      sXT[(ch * 8 + jj) * LDP + r] = f2bf_s(s2f(xv[jj]) * dt);
  }
  if (tid < 64) scum[tid] = cum[(size_t)bh * TLEN + c * CHUNK + tid];
  __syncthreads();

  // phase 1: G[l][s]
  const s16x8 aC0 = *(const s16x8*)(sC + (16 * wave + llo) * LDP + lhi * 8);
  const s16x8 aC1 = *(const s16x8*)(sC + (16 * wave + llo) * LDP + 32 + lhi * 8);
  f32x4 g[4];
#pragma unroll
  for (int j = 0; j < 4; ++j) {
    const s16x8 b0 = *(const s16x8*)(sBW + (16 * j + llo) * LDP + lhi * 8);
    const s16x8 b1 = *(const s16x8*)(sBW + (16 * j + llo) * LDP + 32 + lhi * 8);
    f32x4 acc = fz;
    acc = __builtin_amdgcn_mfma_f32_16x16x32_bf16(aC0, b0, acc, 0, 0, 0);
    acc = __builtin_amdgcn_mfma_f32_16x16x32_bf16(aC1, b1, acc, 0, 0, 0);
    g[j] = acc;
  }
  __syncthreads();

  // phase 2: W[l][s] = (s<=l) ? G*exp(cum[l]-cum[s]) : 0
  float cl[4];
#pragma unroll
  for (int r = 0; r < 4; ++r) cl[r] = scum[16 * wave + lhi * 4 + r];
#pragma unroll
  for (int j = 0; j < 4; ++j) {
    const int s = 16 * j + llo;
    const float cs_ = scum[s];
#pragma unroll
    for (int r = 0; r < 4; ++r) {
      const int l = 16 * wave + lhi * 4 + r;
      const float v = (s <= l) ? g[j][r] * expf(cl[r] - cs_) : 0.f;
      sBW[l * LDP + s] = f2bf_s(v);
    }
  }
  __syncthreads();

  // phase 3: Y[l][p]
  const float el = expf(scum[16 * wave + llo]);
  const s16x8 aCs0 = scale8(aC0, el);
  const s16x8 aCs1 = scale8(aC1, el);
  const s16x8 aW0 = *(const s16x8*)(sBW + (16 * wave + llo) * LDP + lhi * 8);
  const s16x8 aW1 = *(const s16x8*)(sBW + (16 * wave + llo) * LDP + 32 + lhi * 8);
  const float Dh = Dparam[h];
#pragma unroll
  for (int j = 0; j < 4; ++j) {
    const s16x8 bx0 = *(const s16x8*)(sXT + (16 * j + llo) * LDP + lhi * 8);
    const s16x8 bx1 = *(const s16x8*)(sXT + (16 * j + llo) * LDP + 32 + lhi * 8);
    const s16x8 bs0 = *(const s16x8*)(sSP + (16 * j + llo) * LDP + lhi * 8);
    const s16x8 bs1 = *(const s16x8*)(sSP + (16 * j + llo) * LDP + 32 + lhi * 8);
    f32x4 acc = fz;
    acc = __builtin_amdgcn_mfma_f32_16x16x32_bf16(aW0, bx0, acc, 0, 0, 0);
    acc = __builtin_amdgcn_mfma_f32_16x16x32_bf16(aW1, bx1, acc, 0, 0, 0);
    acc = __builtin_amdgcn_mfma_f32_16x16x32_bf16(aCs0, bs0, acc, 0, 0, 0);
    acc = __builtin_amdgcn_mfma_f32_16x16x32_bf16(aCs1, bs1, acc, 0, 0, 0);
#pragma unroll
    for (int r = 0; r < 4; ++r) {
      const int l = 16 * wave + lhi * 4 + r;
      const int p = 16 * j + llo;
      const size_t row = tbase + l;
      const float xval = bf2f(convOut[row * CONVDIM + h * HEADDIM + p]);
      Yraw[row * DINNER + h * HEADDIM + p] = f2bf(acc[r] + Dh * xval);
    }
  }
}

// ---------------- gate (silu(z)) + RMSNorm -> bf16 ----------------
__global__ __launch_bounds__(256) void gate_norm_kernel(
    const __hip_bfloat16* __restrict__ Yraw, const __hip_bfloat16* __restrict__ z,
    const float* __restrict__ norm_w, __hip_bfloat16* __restrict__ ybf) {
  const int row = blockIdx.x;
  const int tid = threadIdx.x;
  const size_t base = (size_t)row * DINNER + tid * 8;
  const s16x8 yv8 = *(const s16x8*)((const short*)Yraw + base);
  const s16x8 zv8 = *(const s16x8*)((const short*)z + base);
  float vals[8];
  float ss = 0.f;
#pragma unroll
  for (int j = 0; j < 8; ++j) {
    const float zv = s2f(zv8[j]);
    const float v = s2f(yv8[j]) * (zv / (1.f + expf(-zv)));
    vals[j] = v;
    ss += v * v;
  }
#pragma unroll
  for (int off = 32; off > 0; off >>= 1) ss += __shfl_down(ss, off, 64);
  __shared__ float red[4];
  if ((tid & 63) == 0) red[tid >> 6] = ss;
  __syncthreads();
  const float rms = rsqrtf((red[0] + red[1] + red[2] + red[3]) / (float)DINNER + 1e-5f);
  const f32x4 nw0 = *(const f32x4*)(norm_w + tid * 8);
  const f32x4 nw1 = *(const f32x4*)(norm_w + tid * 8 + 4);
  s16x8 o;
#pragma unroll
  for (int j = 0; j < 4; ++j) {
    o[j]     = f2bf_s(vals[j] * rms * nw0[j]);
    o[4 + j] = f2bf_s(vals[4 + j] * rms * nw1[j]);
  }
  *(s16x8*)((short*)ybf + base) = o;
}

// ---------------- launch ----------------
extern "C" void kernel_launch(void* const* d_in, const int* in_sizes, int n_in,
                              void* d_out, int out_size, void* d_ws, size_t ws_size,
                              hipStream_t stream) {
  const float* u       = (const float*)d_in[0];
  const float* W_in    = (const float*)d_in[1];
  const float* conv_w  = (const float*)d_in[2];
  const float* conv_b  = (const float*)d_in[3];
  const float* dt_bias = (const float*)d_in[4];
  const float* A_log   = (const float*)d_in[5];
  const float* Dp      = (const float*)d_in[6];
  const float* norm_w  = (const float*)d_in[7];
  const float* W_out   = (const float*)d_in[8];
  float* out = (float*)d_out;

  // --- workspace overlay (peak 148,176,896 bytes — proven layout) ---
  char* w = (char*)d_ws;
  const size_t OFF_WB   = 0;
  const size_t OFF_Z    = OFF_WB  + (size_t)DPROJ * DMODEL * 2;
  const size_t OFF_XBC  = OFF_Z   + (size_t)ROWS * DINNER * 2;
  const size_t OFF_DTR  = OFF_XBC + (size_t)ROWS * CONVDIM * 2;
  const size_t OFF_CONV = OFF_DTR + (size_t)ROWS * NHEADS * 4;
  const size_t OFF_CS   = OFF_CONV+ (size_t)ROWS * CONVDIM * 2;
  const size_t OFF_WOB  = OFF_WB;
  const size_t OFF_DSP  = OFF_WB + (size_t)DMODEL * DINNER * 2;
  const size_t OFF_CUM  = OFF_DSP + (size_t)ROWS * NHEADS * 4;

  __hip_bfloat16* Win_bf  = (__hip_bfloat16*)(w + OFF_WB);
  __hip_bfloat16* Wout_bf = (__hip_bfloat16*)(w + OFF_WOB);
  __hip_bfloat16* Bz      = (__hip_bfloat16*)(w + OFF_Z);
  __hip_bfloat16* Bx      = (__hip_bfloat16*)(w + OFF_XBC);
  float*          Bd      = (float*)(w + OFF_DTR);
  __hip_bfloat16* Bconv   = (__hip_bfloat16*)(w + OFF_CONV);
  float*          dt_sp   = (float*)(w + OFF_DSP);
  float*          cum     = (float*)(w + OFF_CUM);
  __hip_bfloat16* Bcs     = (__hip_bfloat16*)(w + OFF_CS);
  __hip_bfloat16* u_bf    = (__hip_bfloat16*)(w + OFF_CS);
  __hip_bfloat16* Yraw    = Bx;
  __hip_bfloat16* ybf     = Bcs;

  // 0. casts: W_in + u -> bf16 (one dispatch)
  {
    const int n1 = DPROJ * DMODEL, n2 = ROWS * DMODEL;
    cast2_f32_bf16<<<(n1 + n2) / 4 / 256, 256, 0, stream>>>(W_in, Win_bf, n1, u, u_bf, n2);
  }
  // 1. in-projection: 8-phase pipelined kernel, 128x256 tile, grid 64x17
  gemm_8ph_inproj<<<dim3(ROWS / 128, 17), 512, 0, stream>>>(
      (const short*)u_bf, (const short*)Win_bf, Bz, Bx, Bd, DMODEL);
  // 0b. cast W_out -> bf16 (reuses Win_bf region)
  cast_f32_bf16<<<(DMODEL * DINNER / 4 + 255) / 256, 256, 0, stream>>>(W_out, Wout_bf, DMODEL * DINNER);
  // 2. conv + SiLU
  conv_silu_kernel<<<ROWS * 272 / 256, 256, 0, stream>>>(Bx, conv_w, conv_b, Bconv);
  // 3. dt softplus + cumsum (wave-parallel prefix scan)
  dt_cumsum_kernel<<<BSZ * NHEADS * NCHUNK / 4, 256, 0, stream>>>(
      Bd, dt_bias, A_log, dt_sp, cum);
  // 4. per-chunk states
  chunk_state_kernel<<<dim3(NCHUNK, NHEADS, BSZ), 256, 0, stream>>>(Bconv, dt_sp, cum, Bcs);
  // 5. inter-chunk exclusive scan
  scan_kernel<<<(BSZ * NHEADS * HEADDIM * DSTATE) / 256, 256, 0, stream>>>(Bcs, cum);
  // 6. Y
  y_kernel<<<dim3(NCHUNK, NHEADS, BSZ), 256, 0, stream>>>(Bconv, dt_sp, cum, Bcs, Dp, Yraw);
  // 7. gate + RMSNorm
  gate_norm_kernel<<<ROWS, 256, 0, stream>>>(Yraw, Bz, norm_w, ybf);
  // 8. out-projection: r0-proven kernel (4 blocks/CU)
  gemm_tiled<0><<<dim3(ROWS / 128, DMODEL / 128), 256, 0, stream>>>(
      (const short*)ybf, (const short*)Wout_bf, nullptr, nullptr, nullptr, out, ROWS, DMODEL, DINNER);
}